// Round 11
// baseline (117.404 us; speedup 1.0000x reference)
//
#include <hip/hip_runtime.h>
#include <hip/hip_bf16.h>

typedef __bf16 bf16x8 __attribute__((ext_vector_type(8)));
typedef float  f32x4  __attribute__((ext_vector_type(4)));

#define VOCAB 24
#define EDIM  16
#define HDIM  32
#define TLEN  128

union A2U { int4 w; bf16x8 v; };

__device__ __forceinline__ float ex2(float x) { return __builtin_amdgcn_exp2f(x); }
__device__ __forceinline__ float rcpf_(float x) { return __builtin_amdgcn_rcpf(x); }
__device__ __forceinline__ int cvtpk(float lo, float hi) {
    int d;
    asm("v_cvt_pk_bf16_f32 %0, %1, %2" : "=v"(d) : "v"(lo), "v"(hi));
    return d;
}

// WAVE-PRIVATE, SWAPPED-OPERAND design: block = 1 wave = 16 batch rows.
// gates^T = mfma(A = W-fragments, B = h^T / one-hot^T): D[m=gatecol][n=row].
// C-layout (col=lane&15, row=4*(lane>>4)+reg) => lane (l15,hi) holds, for
// batch row l15, gate values of cols 16nt+4hi+s. For hidden j = 16qq+4hi+s:
// i=acc[qq][s], f=acc[2+qq][s], g=acc[4+qq][s], o=acc[6+qq][s] - lane-local.
// Each lane updates 8 (row l15, hidden j) elements; c stays in registers.
// Next step's B-frag needs h[l15][8hi..8hi+7]: values live in same-l15 lanes
// => register-only exchange: 4x v_cvt_pk_bf16_f32 + 8x ds_bpermute + 4 selects
// (no LDS round-trip, no barrier, no store->read ordering).
// A-fragments b1f/b2f are bit-identical to the previous design's B-fragments
// (A and B fragment layouts are symmetric: lane l15 = m/n index, regs = k).
// Activations use the fused-reciprocal form (8 trans/element instead of 10):
//   f       = rcp(1+ew)
//   i*g     = (1-eb)*rcp((1+ea)(1+eb))
//   o*tanh  = (1-eu)*rcp((1+ev)(1+eu))
// with e* = exp2 of the pre-scaled accumulators (B pre-scaled by -log2e /
// -2log2e), eu = exp2(-2*log2e * c_new).
__global__ __launch_bounds__(64) void lstm_fused(
    const int*   __restrict__ x,     // [B][128]
    const float* __restrict__ emb,   // [24][16]
    const float* __restrict__ W_ih,  // [128][16]
    const float* __restrict__ W_hh,  // [128][32]
    const float* __restrict__ b_ih,  // [128]
    const float* __restrict__ b_hh,  // [128]
    const float* __restrict__ fc_w,  // [2][32]
    const float* __restrict__ fc_b,  // [2]
    float*       __restrict__ out)   // [B][2]
{
    __shared__ __align__(16) float fbuf[16][33];   // final h (f32) for FC only

    const int lane  = threadIdx.x;       // 0..63
    const int l15   = lane & 15;
    const int hi    = lane >> 4;         // 0..3
    const int kbase = hi * 8;
    const int kh    = hi * 4;            // packed-word index base
    const int row0  = blockIdx.x * 16;

    // ---- A-fragments for all 8 column tiles, pre-scaled, registers ----
    // tile nt covers gate cols 16nt..16nt+15; gate id = nt>>1 (0=i,1=f,2=g,3=o)
    // A-frag: m = l15 (gatecol within tile), k = kbase + i.
    bf16x8 b1f[8];  // scale * W_hh
    bf16x8 b2f[8];  // scale * (emb[v].W_ih[gcol] + b_ih + b_hh), k = vocab v
    #pragma unroll
    for (int nt = 0; nt < 8; ++nt) {
        const int gcol = nt * 16 + l15;
        const float scale = ((nt >> 1) == 2) ? -2.88539008f : -1.44269504f;
        const float* wrow = W_hh + gcol * HDIM;
        #pragma unroll
        for (int i = 0; i < 8; ++i)
            b1f[nt][i] = (__bf16)(scale * wrow[kbase + i]);
        const float bias = b_ih[gcol] + b_hh[gcol];
        const float* wi = W_ih + gcol * EDIM;
        #pragma unroll
        for (int i = 0; i < 8; ++i) {
            const int v = kbase + i;
            float s = 0.0f;
            if (v < VOCAB) {
                s = bias;
                #pragma unroll
                for (int e = 0; e < EDIM; ++e)
                    s += emb[v * EDIM + e] * wi[e];
            }
            b2f[nt][i] = (__bf16)(scale * s);
        }
    }

    float c[8];
    #pragma unroll
    for (int q = 0; q < 8; ++q) c[q] = 0.0f;

    f32x4 p[8];     // pipelined gates_x accumulators (one-hot MFMAs)
    f32x4 acc[8];
    const f32x4 z = {0.f, 0.f, 0.f, 0.f};
    const int* xrow = x + (row0 + l15) * TLEN;   // tokens of batch row l15

    A2U hb;                                      // h B-fragment (exchanged)
    // exchange source lanes: srcA = l15 + 32*(hi&1), srcB = srcA + 16
    const int addrA = 4 * (l15 + 32 * (hi & 1));
    const int addrB = addrA + 64;
    const bool qsel = (hi >= 2);                 // which qq-pack to take

// one-hot gates_x MFMAs for token XV -> p[]  (one-hot as B-operand)
#define PRECOMP(XV) do {                                                       \
    const int xv_   = (XV);                                                    \
    const int hotw_ = 0x3F80 << ((xv_ & 1) << 4);                              \
    const int hoth_ = xv_ >> 1;                                                \
    A2U a2_;                                                                   \
    a2_.w.x = (hoth_ == kh + 0) ? hotw_ : 0;                                   \
    a2_.w.y = (hoth_ == kh + 1) ? hotw_ : 0;                                   \
    a2_.w.z = (hoth_ == kh + 2) ? hotw_ : 0;                                   \
    a2_.w.w = (hoth_ == kh + 3) ? hotw_ : 0;                                   \
    _Pragma("unroll")                                                          \
    for (int nt = 0; nt < 8; ++nt)                                             \
        p[nt] = __builtin_amdgcn_mfma_f32_16x16x32_bf16(b2f[nt], a2_.v, z, 0, 0, 0); \
} while (0)

// One timestep. On entry p[] holds this step's gates_x, hb the h B-fragment.
#define SLOT(FIRST, LAST, XVN) do {                                            \
    if (FIRST) {                                                               \
        _Pragma("unroll")                                                      \
        for (int nt = 0; nt < 8; ++nt) acc[nt] = p[nt];                        \
    } else {                                                                   \
        _Pragma("unroll")                                                      \
        for (int nt = 0; nt < 8; ++nt)                                         \
            acc[nt] = __builtin_amdgcn_mfma_f32_16x16x32_bf16(b1f[nt], hb.v, p[nt], 0, 0, 0); \
    }                                                                          \
    float hq[2][4];                                                            \
    _Pragma("unroll")                                                          \
    for (int qq = 0; qq < 2; ++qq) {                                           \
        _Pragma("unroll")                                                      \
        for (int s = 0; s < 4; ++s) {                                          \
            const float ea = ex2(acc[qq    ][s]);                              \
            const float ew = ex2(acc[2 + qq][s]);                              \
            const float eb = ex2(acc[4 + qq][s]);                              \
            const float ev = ex2(acc[6 + qq][s]);                              \
            const float R1 = rcpf_(1.0f + ew);                                 \
            const float R2 = rcpf_((1.0f + ea) * (1.0f + eb));                 \
            const float cc = fmaf(c[qq * 4 + s], R1, (1.0f - eb) * R2);        \
            c[qq * 4 + s] = cc;                                                \
            const float eu = ex2(cc * -2.88539008f);                           \
            const float R3 = rcpf_((1.0f + ev) * (1.0f + eu));                 \
            const float hv = (1.0f - eu) * R3;                                 \
            if (LAST) fbuf[l15][qq * 16 + 4 * hi + s] = hv;                    \
            else      hq[qq][s] = hv;                                          \
        }                                                                      \
    }                                                                          \
    if (!(LAST)) {                                                             \
        const int PA0 = cvtpk(hq[0][0], hq[0][1]);                             \
        const int PA1 = cvtpk(hq[0][2], hq[0][3]);                             \
        const int PB0 = cvtpk(hq[1][0], hq[1][1]);                             \
        const int PB1 = cvtpk(hq[1][2], hq[1][3]);                             \
        const int g00 = __builtin_amdgcn_ds_bpermute(addrA, PA0);              \
        const int g01 = __builtin_amdgcn_ds_bpermute(addrA, PB0);              \
        const int g10 = __builtin_amdgcn_ds_bpermute(addrA, PA1);              \
        const int g11 = __builtin_amdgcn_ds_bpermute(addrA, PB1);              \
        const int g20 = __builtin_amdgcn_ds_bpermute(addrB, PA0);              \
        const int g21 = __builtin_amdgcn_ds_bpermute(addrB, PB0);              \
        const int g30 = __builtin_amdgcn_ds_bpermute(addrB, PA1);              \
        const int g31 = __builtin_amdgcn_ds_bpermute(addrB, PB1);              \
        hb.w.x = qsel ? g01 : g00;                                             \
        hb.w.y = qsel ? g11 : g10;                                             \
        hb.w.z = qsel ? g21 : g20;                                             \
        hb.w.w = qsel ? g31 : g30;                                             \
        PRECOMP(XVN);   /* next step's gates_x fills bpermute latency */       \
    }                                                                          \
} while (0)

    // ---- prologue: tokens 0-3 and 4-7; gates_x for t=0 ----
    int4 q0 = *(const int4*)xrow;
    int4 xq = *(const int4*)(xrow + 4);
    PRECOMP(q0.x);

    // t = 0..3
    SLOT(true,  false, q0.y);
    SLOT(false, false, q0.z);
    SLOT(false, false, q0.w);
    SLOT(false, false, xq.x);

    // main: t = 4..123, 4 steps/iter; tokens prefetched one iteration ahead
    #pragma unroll 1
    for (int t = 4; t < 124; t += 4) {
        const int4 n = *(const int4*)(xrow + t + 4);
        SLOT(false, false, xq.y);   // t
        SLOT(false, false, xq.z);   // t+1
        SLOT(false, false, xq.w);   // t+2
        SLOT(false, false, n.x);    // t+3
        xq = n;
    }

    // tail: t = 124..127
    SLOT(false, false, xq.y);       // 124
    SLOT(false, false, xq.z);       // 125
    SLOT(false, false, xq.w);       // 126
    SLOT(false, true,  0);          // 127 -> fbuf (f32)

#undef SLOT
#undef PRECOMP

    __syncthreads();   // single wave: guarantees fbuf writes drained

    // ---- FC epilogue: out[b] = h_last[b] @ fc_w^T + fc_b ----
    if (lane < 16) {
        float o0 = fc_b[0], o1 = fc_b[1];
        #pragma unroll
        for (int jj = 0; jj < HDIM; ++jj) {
            const float h = fbuf[lane][jj];
            o0 += fc_w[jj]        * h;
            o1 += fc_w[HDIM + jj] * h;
        }
        float2 res;
        res.x = o0; res.y = o1;
        *(float2*)&out[(row0 + lane) * 2] = res;
    }
}

extern "C" void kernel_launch(void* const* d_in, const int* in_sizes, int n_in,
                              void* d_out, int out_size, void* d_ws, size_t ws_size,
                              hipStream_t stream) {
    const int*   x    = (const int*)  d_in[0];
    const float* emb  = (const float*)d_in[1];
    const float* W_ih = (const float*)d_in[2];
    const float* W_hh = (const float*)d_in[3];
    const float* b_ih = (const float*)d_in[4];
    const float* b_hh = (const float*)d_in[5];
    const float* fc_w = (const float*)d_in[6];
    const float* fc_b = (const float*)d_in[7];
    float* out = (float*)d_out;

    const int B    = in_sizes[0] / TLEN;   // 16384
    const int nblk = B / 16;               // 1024 waves, 1 per SIMD chip-wide

    lstm_fused<<<nblk, 64, 0, stream>>>(x, emb, W_ih, W_hh, b_ih, b_hh, fc_w, fc_b, out);
}